// Round 18
// baseline (79.627 us; speedup 1.0000x reference)
//
#include <hip/hip_runtime.h>
#include <hip/hip_bf16.h>
#include <math.h>

#define S_LEN 2048
#define E_DIM 1024
#define NHEAD 8
#define DHEAD 128
#define MEPS 1e-6f
#define LNEPS 1e-5f
#define TASKS_PER_HEAD 72   // sum over qg of ceil((4qg+4)/8)

typedef __bf16 bf16x8 __attribute__((ext_vector_type(8)));
typedef __bf16 bf16x4 __attribute__((ext_vector_type(4)));
typedef float f32x4 __attribute__((ext_vector_type(4)));
typedef float f32x16 __attribute__((ext_vector_type(16)));

__device__ __host__ inline int ns_of(int qg) { return (4 * qg + 11) / 8; }

__device__ inline void split8(const float* x, bf16x8& hi, bf16x8& lo) {
#pragma unroll
  for (int e = 0; e < 8; ++e) {
    float v = x[e];
    __bf16 h = (__bf16)v;
    hi[e] = h;
    lo[e] = (__bf16)(v - (float)h);
  }
}

__device__ inline int cvtpk(float a, float b) {
  int d;
  asm("v_cvt_pk_bf16_f32 %0, %1, %2" : "=v"(d) : "v"(a), "v"(b));
  return d;
}

// ---------- kernel A: fused convert (blocks 0..511) + wfrag (blocks 512..535) ----------
__global__ __launch_bounds__(256) void convw_kernel(
    const float* __restrict__ k, const float* __restrict__ v,
    const float* __restrict__ igw, const float* __restrict__ fgw,
    __bf16* __restrict__ KfH, __bf16* __restrict__ KfL, __bf16* __restrict__ VT,
    __bf16* __restrict__ WfH, __bf16* __restrict__ WfL) {
  __shared__ float Kl[32][132], Vl[32][132];
  int t = threadIdx.x;
  if (blockIdx.x >= 512) {   // ---- wfrag ----
    int slot = (blockIdx.x - 512) * 256 + t;   // 6144
    int f = slot >> 6, l = slot & 63;
    int c = l & 15;
    int koff = f * 32 + (l >> 4) * 8;
    const float* wrow = (c < 8) ? (igw + c * 3072) : (fgw + (c - 8) * 3072);
    float buf[8];
#pragma unroll
    for (int e = 0; e < 8; ++e) buf[e] = wrow[koff + e];
    bf16x8 fh, fl; split8(buf, fh, fl);
    *(bf16x8*)(WfH + (size_t)slot * 8) = fh;
    *(bf16x8*)(WfL + (size_t)slot * 8) = fl;
    return;
  }
  // ---- convert ----
  int h = blockIdx.x >> 6, kvt = blockIdx.x & 63;
  int kvbase = kvt * 32;
#pragma unroll
  for (int it = 0; it < 4; ++it) {
    int fid = it * 256 + t;
    int r = fid >> 5, c4 = (fid & 31) * 4;
    *(float4*)&Kl[r][c4] = *(const float4*)(k + (size_t)(kvbase + r) * E_DIM + h * DHEAD + c4);
    *(float4*)&Vl[r][c4] = *(const float4*)(v + (size_t)(kvbase + r) * E_DIM + h * DHEAD + c4);
  }
  __syncthreads();
  size_t tb = (size_t)(h * 64 + kvt) * 4096;
#pragma unroll
  for (int it = 0; it < 2; ++it) {
    int slot = it * 256 + t;
    int f = slot >> 6, l = slot & 63;
    int l31 = l & 31, hi = l >> 5;
    {
      float buf[8];
#pragma unroll
      for (int e = 0; e < 8; ++e) buf[e] = Kl[l31][f * 16 + hi * 8 + e];
      bf16x8 fh, fl; split8(buf, fh, fl);
      *(bf16x8*)(KfH + tb + (size_t)slot * 8) = fh;
      *(bf16x8*)(KfL + tb + (size_t)slot * 8) = fl;
    }
    {
      int dt = f >> 1, kch = f & 1;
      bf16x8 fh;
#pragma unroll
      for (int e = 0; e < 8; ++e) fh[e] = (__bf16)Vl[kch * 16 + hi * 8 + e][dt * 32 + l31];
      *(bf16x8*)(VT + tb + (size_t)slot * 8) = fh;
    }
  }
}

// ---------- kernel 1: gates GEMM via split-bf16 MFMA ----------
__global__ __launch_bounds__(256) void gates_mfma_kernel(
    const float* __restrict__ q, const float* __restrict__ k, const float* __restrict__ v,
    const __bf16* __restrict__ WfH, const __bf16* __restrict__ WfL,
    float* __restrict__ gpart) {
  int rb = blockIdx.x >> 3;
  int ks = blockIdx.x & 7;
  int r0 = rb * 64;
  int tid = threadIdx.x, wave = tid >> 6, lane = tid & 63;
  int l15 = lane & 15, hi = lane >> 4;
  __shared__ char Xl[64 * 512];

  f32x4 cacc = (f32x4){0.f, 0.f, 0.f, 0.f};
  for (int ch = 0; ch < 3; ++ch) {
    int kb = ks * 384 + ch * 128;
    __syncthreads();
#pragma unroll
    for (int it = 0; it < 8; ++it) {
      int fid = it * 256 + tid;
      int row = fid >> 5, c4 = (fid & 31) * 4;
      int kk = kb + c4;
      const float* src = (kk < 1024) ? (q + (size_t)(r0 + row) * 1024 + kk)
                       : (kk < 2048) ? (k + (size_t)(r0 + row) * 1024 + (kk - 1024))
                                     : (v + (size_t)(r0 + row) * 1024 + (kk - 2048));
      float4 xv = *(const float4*)src;
      *(float4*)(Xl + ((row * 512 + c4 * 4) ^ ((row & 7) << 4))) = xv;
    }
    __syncthreads();
#pragma unroll
    for (int kc = 0; kc < 4; ++kc) {
      int row = wave * 16 + l15;
      int base = row * 512 + (kc * 32 + hi * 8) * 4;
      int x = (row & 7) << 4;
      float buf[8];
      *(float4*)&buf[0] = *(const float4*)(Xl + (base ^ x));
      *(float4*)&buf[4] = *(const float4*)(Xl + ((base + 16) ^ x));
      bf16x8 ah, al; split8(buf, ah, al);
      int gkc = ks * 12 + ch * 4 + kc;
      bf16x8 bh = *(const bf16x8*)(WfH + (size_t)(gkc * 64 + lane) * 8);
      bf16x8 bl = *(const bf16x8*)(WfL + (size_t)(gkc * 64 + lane) * 8);
      cacc = __builtin_amdgcn_mfma_f32_16x16x32_bf16(ah, bh, cacc, 0, 0, 0);
      cacc = __builtin_amdgcn_mfma_f32_16x16x32_bf16(ah, bl, cacc, 0, 0, 0);
      cacc = __builtin_amdgcn_mfma_f32_16x16x32_bf16(al, bh, cacc, 0, 0, 0);
    }
  }
#pragma unroll
  for (int rg = 0; rg < 4; ++rg) {
    int r = r0 + wave * 16 + hi * 4 + rg;
    gpart[((size_t)ks * S_LEN + r) * 16 + l15] = cacc[rg];
  }
}

// ---------- kernel 1b: sum K-split partials + bias; ig f32, fg -> f64 logsig ----------
__global__ __launch_bounds__(256) void combine_ls_kernel(
    const float* __restrict__ gpart, const float* __restrict__ igb,
    const float* __restrict__ fgb, float* __restrict__ ig, double* __restrict__ ls) {
  int t = blockIdx.x * 256 + threadIdx.x;
  int r = t >> 4, c = t & 15;
  float s = 0.f;
#pragma unroll
  for (int ks = 0; ks < 8; ++ks) s += gpart[((size_t)ks * S_LEN + r) * 16 + c];
  if (c < 8) {
    ig[c * S_LEN + r] = s + igb[c];
  } else {
    double x = (double)(s + fgb[c - 8]);
    ls[(c - 8) * S_LEN + r] = fmin(x, 0.0) - log1p(exp(-fabs(x)));
  }
}

// ---------- kernel 2: fused per-head f64 scan + rebase (1 block/head, 256 thr) ----------
__global__ __launch_bounds__(256) void scanreb_kernel(
    const float* __restrict__ ig, const double* __restrict__ ls,
    float* __restrict__ gq, float* __restrict__ Mq, float* __restrict__ rexpv) {
  int h = blockIdx.x;
  int tid = threadIdx.x;
  __shared__ double Lg[2048];    // 16KB
  __shared__ double Lcs[2048];   // 16KB
  __shared__ double LM[2048];    // 16KB (48KB total)

  if (tid < 64) {               // wave-0 scan, math identical to prior scan_kernel
    int lane = tid;
    double cs0[32];
    const double* lsp = ls + h * S_LEN + lane * 32;
    double run = 0.0;
#pragma unroll
    for (int e = 0; e < 32; ++e) { run += lsp[e]; cs0[e] = run; }
    double incl = run;
#pragma unroll
    for (int off = 1; off < 64; off <<= 1) {
      double nb = __shfl_up(incl, off);
      if (lane >= off) incl += nb;
    }
    double base = __shfl_up(incl, 1);
    if (lane == 0) base = 0.0;
#pragma unroll
    for (int e = 0; e < 32; ++e) cs0[e] += base;

    const float* igp = ig + h * S_LEN + lane * 32;
    double gv[32];
#pragma unroll
    for (int e = 0; e < 32; ++e) {
      gv[e] = (double)igp[e] - cs0[e];
      Lg[lane * 32 + e] = gv[e];
      Lcs[lane * 32 + e] = cs0[e];
    }
    double pm = -INFINITY;
#pragma unroll
    for (int e = 0; e < 32; ++e) { pm = fmax(pm, gv[e]); gv[e] = pm; }
    double inclm = pm;
#pragma unroll
    for (int off = 1; off < 64; off <<= 1) {
      double nb = __shfl_up(inclm, off);
      if (lane >= off) inclm = fmax(inclm, nb);
    }
    double basem = __shfl_up(inclm, 1);
    if (lane == 0) basem = -INFINITY;
#pragma unroll
    for (int e = 0; e < 32; ++e) LM[lane * 32 + e] = fmax(basem, gv[e]);
  }
  __syncthreads();

  const double L2E = 1.4426950408889634;
#pragma unroll
  for (int it = 0; it < 8; ++it) {
    int i = it * 256 + tid;
    int qgi = i >> 7;
    Mq[h * S_LEN + i] = (float)((LM[i] - LM[qgi * 128]) * L2E);
    rexpv[h * S_LEN + i] = __expf(-(float)(Lcs[i] + LM[i]));
  }
  for (int qg = 0; qg < 16; ++qg) {
    double base = LM[qg * 128];
    float* dst = gq + (size_t)(h * 16 + qg) * S_LEN;
#pragma unroll
    for (int it = 0; it < 8; ++it) {
      int j = it * 256 + tid;
      dst[j] = (float)((Lg[j] - base) * L2E);
    }
  }
}

// ---------- kernel 4: attention, 2-buf 48KB, 1 barrier/tile, max-8-tile kv-splits ----------
__global__ __launch_bounds__(256, 2) void attn_kernel(
    const float* __restrict__ q,
    const __bf16* __restrict__ KfH, const __bf16* __restrict__ KfL,
    const __bf16* __restrict__ VT,
    const float* __restrict__ gq, const float* __restrict__ Mq,
    __bf16* __restrict__ part, float* __restrict__ bpart) {
  // decode: heavy-first (qg=15 first); block counts per qg = 8*ns(qg)
  int rem = blockIdx.x;
  int qg = 15, preLow = 0, ns = 1;
  for (int qq = 15; qq >= 0; --qq) {
    int n = ns_of(qq);
    if (rem < 8 * n) { qg = qq; ns = n; break; }
    rem -= 8 * n;
  }
  for (int qq = 0; qq < qg; ++qq) preLow += ns_of(qq);
  int h = rem & 7;                   // head -> XCD pinned
  int split = rem >> 3;
  int T = 4 * qg + 4;
  int kb_lo = (split * T) / ns;
  int kb_hi = ((split + 1) * T) / ns;
  int Tq = kb_hi - kb_lo;            // <= 8
  int tid = threadIdx.x, wave = tid >> 6, lane = tid & 63;
  int l31 = lane & 31, hi = lane >> 5;
  const float scale = 0.08838834764831845f;

  __shared__ char smem[49152];       // 2 bufs x [KH 8K | KL 8K | VT 8K]

  int qrow = qg * 128 + wave * 32 + l31;
  bf16x8 qfh[8], qfl[8];
  {
    const float* qp = q + (size_t)qrow * E_DIM + h * DHEAD + hi * 8;
#pragma unroll
    for (int kch = 0; kch < 8; ++kch) {
      float buf[8];
      *(float4*)&buf[0] = *(const float4*)(qp + kch * 16);
      *(float4*)&buf[4] = *(const float4*)(qp + kch * 16 + 4);
#pragma unroll
      for (int e = 0; e < 8; ++e) buf[e] *= scale;
      split8(buf, qfh[kch], qfl[kch]);
    }
  }
  float Mreg = Mq[h * S_LEN + qrow];
  const float* gqh = gq + (size_t)(h * 16 + qg) * S_LEN;

  f32x16 acc[4];
#pragma unroll
  for (int dt = 0; dt < 4; ++dt) acc[dt] = (f32x16)(0.f);
  float bacc = 0.f;

  size_t laneoff = (size_t)lane * 8;
  auto STAGE = [&](int kb, int buf) {
    size_t tb = (size_t)(h * 64 + kb) * 4096;
    char* lb = smem + buf * 24576;
#pragma unroll
    for (int i = 0; i < 6; ++i) {
      int c = wave * 6 + i;
      const __bf16* src;
      if (c < 8)       src = KfH + tb + (size_t)c * 512 + laneoff;
      else if (c < 16) src = KfL + tb + (size_t)(c - 8) * 512 + laneoff;
      else             src = VT  + tb + (size_t)(c - 16) * 512 + laneoff;
      __builtin_amdgcn_global_load_lds(
          (const __attribute__((address_space(1))) void*)src,
          (__attribute__((address_space(3))) void*)(lb + c * 1024), 16, 0, 0);
    }
  };

  if (Tq > 0) STAGE(kb_lo, 0);
  int cur = 0;
  for (int t = 0; t < Tq; ++t) {
    int kb = kb_lo + t;
    // wait own tile-t chunks; barrier proves (a) all tile-t chunks landed,
    // (b) all waves finished tile t-1 -> buffer cur^1 free for restage.
    asm volatile("s_waitcnt vmcnt(0)" ::: "memory");
    __builtin_amdgcn_sched_barrier(0);
    asm volatile("s_barrier" ::: "memory");
    if (t + 1 < Tq) STAGE(kb + 1, cur ^ 1);   // flies during compute of tile t

    int qrelw = qg * 128 + wave * 32 - kb * 32;
    if (qrelw + 31 >= 0) {
      char* lb = smem + cur * 24576;
      int qrel = qrelw + l31;
      float4 g4[4];
#pragma unroll
      for (int c = 0; c < 4; ++c) g4[c] = *(const float4*)(gqh + kb * 32 + 8 * c + 4 * hi);
      // ---- S^T: 3 independent 8-MFMA chains (hh, lh, hl) ----
      f32x16 sA = (f32x16)(0.f), sB = (f32x16)(0.f), sC = (f32x16)(0.f);
      __builtin_amdgcn_s_setprio(1);
#pragma unroll
      for (int kch = 0; kch < 8; ++kch) {
        bf16x8 kh = *(const bf16x8*)(lb + kch * 1024 + lane * 16);
        bf16x8 kl = *(const bf16x8*)(lb + 8192 + kch * 1024 + lane * 16);
        sA = __builtin_amdgcn_mfma_f32_32x32x16_bf16(kh, qfh[kch], sA, 0, 0, 0);
        sB = __builtin_amdgcn_mfma_f32_32x32x16_bf16(kl, qfh[kch], sB, 0, 0, 0);
        sC = __builtin_amdgcn_mfma_f32_32x32x16_bf16(kh, qfl[kch], sC, 0, 0, 0);
      }
      __builtin_amdgcn_s_setprio(0);
      float p[16];
      float bp0 = 0.f, bp1 = 0.f, bp2 = 0.f, bp3 = 0.f;
      if (qrelw >= 31) {           // interior tile: no causal mask
#pragma unroll
        for (int rg = 0; rg < 16; ++rg) {
          float sv = sA[rg] + sB[rg] + sC[rg];
          p[rg] = sv * exp2f(((const float*)&g4[rg >> 2])[rg & 3] - Mreg);
          if ((rg & 3) == 0) bp0 += p[rg];
          else if ((rg & 3) == 1) bp1 += p[rg];
          else if ((rg & 3) == 2) bp2 += p[rg];
          else bp3 += p[rg];
        }
      } else {                     // diagonal tile
#pragma unroll
        for (int rg = 0; rg < 16; ++rg) {
          int J = (rg & 3) + 8 * (rg >> 2) + 4 * hi;
          float sv = sA[rg] + sB[rg] + sC[rg];
          float w = sv * exp2f(((const float*)&g4[rg >> 2])[rg & 3] - Mreg);
          p[rg] = (J <= qrel) ? w : 0.f;
          if ((rg & 3) == 0) bp0 += p[rg];
          else if ((rg & 3) == 1) bp1 += p[rg];
          else if ((rg & 3) == 2) bp2 += p[rg];
          else bp3 += p[rg];
        }
      }
      bacc += (bp0 + bp1) + (bp2 + bp3);
#pragma unroll
      for (int kch = 0; kch < 2; ++kch) {
        const float* pp = p + kch * 8;
        int a0 = cvtpk(pp[0], pp[1]);
        int a1 = cvtpk(pp[2], pp[3]);
        int a2 = cvtpk(pp[4], pp[5]);
        int a3 = cvtpk(pp[6], pp[7]);
        asm("v_permlane32_swap_b32 %0, %1" : "+v"(a0), "+v"(a2));
        asm("v_permlane32_swap_b32 %0, %1" : "+v"(a1), "+v"(a3));
        union { int w[4]; bf16x8 v; } pb;
        pb.w[0] = a0; pb.w[1] = a1; pb.w[2] = a2; pb.w[3] = a3;
        __builtin_amdgcn_s_setprio(1);
#pragma unroll
        for (int dt = 0; dt < 4; ++dt) {
          bf16x8 va = *(const bf16x8*)(lb + 16384 + (dt * 2 + kch) * 1024 + lane * 16);
          acc[dt] = __builtin_amdgcn_mfma_f32_32x32x16_bf16(va, pb.v, acc[dt], 0, 0, 0);
        }
        __builtin_amdgcn_s_setprio(0);
      }
    }
    cur ^= 1;    // next iter's top barrier is the sync point
  }

  // epilogue: b-combine; transpose O^T -> q-major via LDS; coalesced part writes
  {
    int x = __float_as_int(bacc), y = x;
    asm("v_permlane32_swap_b32 %0, %1" : "+v"(x), "+v"(y));
    float bfull = __int_as_float(x) + __int_as_float(y);
    int task = h * TASKS_PER_HEAD + preLow + split;
    if (lane < 32) bpart[task * 128 + wave * 32 + lane] = bfull;

    __syncthreads();                       // all waves done with K/V buffers
    char* Tls = smem + wave * 8704;        // 32 q x 272B
#pragma unroll
    for (int dt = 0; dt < 4; ++dt)
#pragma unroll
      for (int rgq = 0; rgq < 4; ++rgq) {
        bf16x4 pk;
        pk[0] = (__bf16)acc[dt][rgq * 4 + 0];
        pk[1] = (__bf16)acc[dt][rgq * 4 + 1];
        pk[2] = (__bf16)acc[dt][rgq * 4 + 2];
        pk[3] = (__bf16)acc[dt][rgq * 4 + 3];
        int d0 = dt * 32 + rgq * 8 + hi * 4;
        *(bf16x4*)(Tls + l31 * 272 + d0 * 2) = pk;
      }
    __syncthreads();
    __bf16* pp = part + (size_t)task * 16384;   // [128 q][128 d]
#pragma unroll
    for (int it = 0; it < 8; ++it) {
      int qr = it * 4 + (lane >> 4);
      int chunk = lane & 15;
      bf16x8 vrow = *(const bf16x8*)(Tls + qr * 272 + chunk * 16);
      *(bf16x8*)(pp + ((size_t)(wave * 32 + qr) * 128 + chunk * 8)) = vrow;
    }
  }
}

// ---------- kernel 5: fused combine + normalize + LayerNorm (variable ns) ----------
__global__ __launch_bounds__(256) void cln_kernel(
    const __bf16* __restrict__ part, const float* __restrict__ bpart,
    const float* __restrict__ rexpv, const float* __restrict__ lnw,
    float* __restrict__ out) {
  int b = blockIdx.x;            // 256 = qg*16 + slab
  int qg = b >> 4, slab = b & 15;
  int ns = ns_of(qg);
  int preLow = 0;
  for (int qq = 0; qq < qg; ++qq) preLow += ns_of(qq);
  int tid = threadIdx.x;
  int tokl = tid >> 5;
  int j = tid & 31;
  int qv = slab * 8 + tokl;
  int tok = qg * 128 + qv;
  int h = j >> 2;
  int d0 = (j & 3) * 32;
  int task0 = h * TASKS_PER_HEAD + preLow;

  float a[32];
#pragma unroll
  for (int i = 0; i < 32; ++i) a[i] = 0.f;
  float bb = 0.f;
  for (int s = 0; s < ns; ++s) {
    const __bf16* pp = part + (size_t)(task0 + s) * 16384 + qv * 128 + d0;
#pragma unroll
    for (int c = 0; c < 4; ++c) {
      bf16x8 xv = *(const bf16x8*)(pp + c * 8);
#pragma unroll
      for (int e = 0; e < 8; ++e) a[c * 8 + e] += (float)xv[e];
    }
    bb += bpart[(task0 + s) * 128 + qv];
  }
  float norm = fmaxf(fabsf(bb), rexpv[h * S_LEN + tok]) + MEPS;
  float inv = 1.f / norm;
  float sum = 0.f, sq = 0.f;
#pragma unroll
  for (int i = 0; i < 32; ++i) {
    a[i] *= inv;
    sum += a[i];
    sq += a[i] * a[i];
  }
#pragma unroll
  for (int off = 1; off < 32; off <<= 1) {
    sum += __shfl_xor(sum, off);
    sq  += __shfl_xor(sq, off);
  }
  float mu = sum * (1.f / E_DIM);
  float var = sq * (1.f / E_DIM) - mu * mu;
  float rstd = rsqrtf(var + LNEPS);
  float* dst = out + (size_t)tok * E_DIM + j * 32;
  const float* wsrc = lnw + j * 32;
#pragma unroll
  for (int c = 0; c < 8; ++c) {
    float4 w = *(const float4*)(wsrc + c * 4);
    float4 o;
    o.x = (a[c * 4 + 0] - mu) * rstd * w.x;
    o.y = (a[c * 4 + 1] - mu) * rstd * w.y;
    o.z = (a[c * 4 + 2] - mu) * rstd * w.z;
    o.w = (a[c * 4 + 3] - mu) * rstd * w.w;
    *(float4*)(dst + c * 4) = o;
  }
}

extern "C" void kernel_launch(void* const* d_in, const int* in_sizes, int n_in,
                              void* d_out, int out_size, void* d_ws, size_t ws_size,
                              hipStream_t stream) {
  const float* q   = (const float*)d_in[0];
  const float* k   = (const float*)d_in[1];
  const float* v   = (const float*)d_in[2];
  const float* igw = (const float*)d_in[3];
  const float* igb = (const float*)d_in[4];
  const float* fgw = (const float*)d_in[5];
  const float* fgb = (const float*)d_in[6];
  const float* lnw = (const float*)d_in[7];
  float* out = (float*)d_out;

  const size_t MB = 1024 * 1024;
  char* base = (char*)d_ws;
  float*  ig    = (float*)(base + 0);               // 64KB
  float*  rexpv = (float*)(base + 64 * 1024);       // 64KB
  float*  Mq    = (float*)(base + 128 * 1024);      // 64KB
  float*  bpart = (float*)(base + 192 * 1024);      // 576*128*4 = 294KB (<512KB)
  double* ls    = (double*)(base + 704 * 1024);     // 128KB
  __bf16* WfH   = (__bf16*)(base + 1088 * 1024);    // 96KB
  __bf16* WfL   = (__bf16*)(base + 1184 * 1024);    // 96KB
  float*  gq    = (float*)(base + 1536 * 1024);     // 1MB (ends 2.5MB)
  __bf16* KfH   = (__bf16*)(base + 3 * MB);         // 4MB
  __bf16* KfL   = (__bf16*)(base + 7 * MB);         // 4MB
  __bf16* VT    = (__bf16*)(base + 11 * MB);        // 4MB
  __bf16* part  = (__bf16*)(base + 15 * MB);        // 576 tasks x 32KB = 18MB (ends 33MB)
  float*  gpart = (float*)(base + 33 * MB);         // 1MB (footprint 34MB; ws>=48MB proven)

  int nblocks = 8 * TASKS_PER_HEAD;                 // 576

  convw_kernel<<<dim3(536), dim3(256), 0, stream>>>(k, v, igw, fgw, KfH, KfL, VT, WfH, WfL);
  gates_mfma_kernel<<<dim3(256), dim3(256), 0, stream>>>(q, k, v, WfH, WfL, gpart);
  combine_ls_kernel<<<dim3(128), dim3(256), 0, stream>>>(gpart, igb, fgb, ig, ls);
  scanreb_kernel<<<dim3(NHEAD), dim3(256), 0, stream>>>(ig, ls, gq, Mq, rexpv);
  attn_kernel<<<dim3(nblocks), dim3(256), 0, stream>>>(q, KfH, KfL, VT, gq, Mq, part, bpart);
  cln_kernel<<<dim3(256), dim3(256), 0, stream>>>(part, bpart, rexpv, lnw, out);
}

// Round 19
// 70.916 us; speedup vs baseline: 1.1228x; 1.1228x over previous
//
#include <hip/hip_runtime.h>
#include <hip/hip_bf16.h>
#include <math.h>

#define S_LEN 2048
#define E_DIM 1024
#define NHEAD 8
#define DHEAD 128
#define MEPS 1e-6f
#define LNEPS 1e-5f
#define TASKS_PER_HEAD 61   // sum over qg of ceil((4qg+4)/10)

typedef __bf16 bf16x8 __attribute__((ext_vector_type(8)));
typedef __bf16 bf16x4 __attribute__((ext_vector_type(4)));
typedef float f32x4 __attribute__((ext_vector_type(4)));
typedef float f32x16 __attribute__((ext_vector_type(16)));

__device__ __host__ inline int ns_of(int qg) { return (4 * qg + 13) / 10; }

__device__ inline void split8(const float* x, bf16x8& hi, bf16x8& lo) {
#pragma unroll
  for (int e = 0; e < 8; ++e) {
    float v = x[e];
    __bf16 h = (__bf16)v;
    hi[e] = h;
    lo[e] = (__bf16)(v - (float)h);
  }
}

__device__ inline int cvtpk(float a, float b) {
  int d;
  asm("v_cvt_pk_bf16_f32 %0, %1, %2" : "=v"(d) : "v"(a), "v"(b));
  return d;
}

// ---------- kernel A: fused convert (blocks 0..511) + wfrag (blocks 512..535) ----------
__global__ __launch_bounds__(256) void convw_kernel(
    const float* __restrict__ k, const float* __restrict__ v,
    const float* __restrict__ igw, const float* __restrict__ fgw,
    __bf16* __restrict__ KfH, __bf16* __restrict__ KfL, __bf16* __restrict__ VT,
    __bf16* __restrict__ WfH, __bf16* __restrict__ WfL) {
  __shared__ float Kl[32][132], Vl[32][132];
  int t = threadIdx.x;
  if (blockIdx.x >= 512) {   // ---- wfrag ----
    int slot = (blockIdx.x - 512) * 256 + t;   // 6144
    int f = slot >> 6, l = slot & 63;
    int c = l & 15;
    int koff = f * 32 + (l >> 4) * 8;
    const float* wrow = (c < 8) ? (igw + c * 3072) : (fgw + (c - 8) * 3072);
    float buf[8];
#pragma unroll
    for (int e = 0; e < 8; ++e) buf[e] = wrow[koff + e];
    bf16x8 fh, fl; split8(buf, fh, fl);
    *(bf16x8*)(WfH + (size_t)slot * 8) = fh;
    *(bf16x8*)(WfL + (size_t)slot * 8) = fl;
    return;
  }
  // ---- convert ----
  int h = blockIdx.x >> 6, kvt = blockIdx.x & 63;
  int kvbase = kvt * 32;
#pragma unroll
  for (int it = 0; it < 4; ++it) {
    int fid = it * 256 + t;
    int r = fid >> 5, c4 = (fid & 31) * 4;
    *(float4*)&Kl[r][c4] = *(const float4*)(k + (size_t)(kvbase + r) * E_DIM + h * DHEAD + c4);
    *(float4*)&Vl[r][c4] = *(const float4*)(v + (size_t)(kvbase + r) * E_DIM + h * DHEAD + c4);
  }
  __syncthreads();
  size_t tb = (size_t)(h * 64 + kvt) * 4096;
#pragma unroll
  for (int it = 0; it < 2; ++it) {
    int slot = it * 256 + t;
    int f = slot >> 6, l = slot & 63;
    int l31 = l & 31, hi = l >> 5;
    {
      float buf[8];
#pragma unroll
      for (int e = 0; e < 8; ++e) buf[e] = Kl[l31][f * 16 + hi * 8 + e];
      bf16x8 fh, fl; split8(buf, fh, fl);
      *(bf16x8*)(KfH + tb + (size_t)slot * 8) = fh;
      *(bf16x8*)(KfL + tb + (size_t)slot * 8) = fl;
    }
    {
      int dt = f >> 1, kch = f & 1;
      bf16x8 fh;
#pragma unroll
      for (int e = 0; e < 8; ++e) fh[e] = (__bf16)Vl[kch * 16 + hi * 8 + e][dt * 32 + l31];
      *(bf16x8*)(VT + tb + (size_t)slot * 8) = fh;
    }
  }
}

// ---------- kernel 1: gates GEMM via split-bf16 MFMA ----------
__global__ __launch_bounds__(256) void gates_mfma_kernel(
    const float* __restrict__ q, const float* __restrict__ k, const float* __restrict__ v,
    const __bf16* __restrict__ WfH, const __bf16* __restrict__ WfL,
    float* __restrict__ gpart) {
  int rb = blockIdx.x >> 3;
  int ks = blockIdx.x & 7;
  int r0 = rb * 64;
  int tid = threadIdx.x, wave = tid >> 6, lane = tid & 63;
  int l15 = lane & 15, hi = lane >> 4;
  __shared__ char Xl[64 * 512];

  f32x4 cacc = (f32x4){0.f, 0.f, 0.f, 0.f};
  for (int ch = 0; ch < 3; ++ch) {
    int kb = ks * 384 + ch * 128;
    __syncthreads();
#pragma unroll
    for (int it = 0; it < 8; ++it) {
      int fid = it * 256 + tid;
      int row = fid >> 5, c4 = (fid & 31) * 4;
      int kk = kb + c4;
      const float* src = (kk < 1024) ? (q + (size_t)(r0 + row) * 1024 + kk)
                       : (kk < 2048) ? (k + (size_t)(r0 + row) * 1024 + (kk - 1024))
                                     : (v + (size_t)(r0 + row) * 1024 + (kk - 2048));
      float4 xv = *(const float4*)src;
      *(float4*)(Xl + ((row * 512 + c4 * 4) ^ ((row & 7) << 4))) = xv;
    }
    __syncthreads();
#pragma unroll
    for (int kc = 0; kc < 4; ++kc) {
      int row = wave * 16 + l15;
      int base = row * 512 + (kc * 32 + hi * 8) * 4;
      int x = (row & 7) << 4;
      float buf[8];
      *(float4*)&buf[0] = *(const float4*)(Xl + (base ^ x));
      *(float4*)&buf[4] = *(const float4*)(Xl + ((base + 16) ^ x));
      bf16x8 ah, al; split8(buf, ah, al);
      int gkc = ks * 12 + ch * 4 + kc;
      bf16x8 bh = *(const bf16x8*)(WfH + (size_t)(gkc * 64 + lane) * 8);
      bf16x8 bl = *(const bf16x8*)(WfL + (size_t)(gkc * 64 + lane) * 8);
      cacc = __builtin_amdgcn_mfma_f32_16x16x32_bf16(ah, bh, cacc, 0, 0, 0);
      cacc = __builtin_amdgcn_mfma_f32_16x16x32_bf16(ah, bl, cacc, 0, 0, 0);
      cacc = __builtin_amdgcn_mfma_f32_16x16x32_bf16(al, bh, cacc, 0, 0, 0);
    }
  }
#pragma unroll
  for (int rg = 0; rg < 4; ++rg) {
    int r = r0 + wave * 16 + hi * 4 + rg;
    gpart[((size_t)ks * S_LEN + r) * 16 + l15] = cacc[rg];
  }
}

// ---------- kernel 1b: sum K-split partials + bias; ig f32, fg -> f64 logsig ----------
__global__ __launch_bounds__(256) void combine_ls_kernel(
    const float* __restrict__ gpart, const float* __restrict__ igb,
    const float* __restrict__ fgb, float* __restrict__ ig, double* __restrict__ ls) {
  int t = blockIdx.x * 256 + threadIdx.x;
  int r = t >> 4, c = t & 15;
  float s = 0.f;
#pragma unroll
  for (int ks = 0; ks < 8; ++ks) s += gpart[((size_t)ks * S_LEN + r) * 16 + c];
  if (c < 8) {
    ig[c * S_LEN + r] = s + igb[c];
  } else {
    double x = (double)(s + fgb[c - 8]);
    ls[(c - 8) * S_LEN + r] = fmin(x, 0.0) - log1p(exp(-fabs(x)));
  }
}

// ---------- kernel 2: fused per-head f64 scan + rebase (1 block/head, 256 thr) ----------
__global__ __launch_bounds__(256) void scanreb_kernel(
    const float* __restrict__ ig, const double* __restrict__ ls,
    float* __restrict__ gq, float* __restrict__ Mq, float* __restrict__ rexpv) {
  int h = blockIdx.x;
  int tid = threadIdx.x;
  __shared__ double Lg[2048];    // 16KB
  __shared__ double Lcs[2048];   // 16KB
  __shared__ double LM[2048];    // 16KB (48KB total)

  if (tid < 64) {               // wave-0 scan, math identical to prior scan_kernel
    int lane = tid;
    double cs0[32];
    const double* lsp = ls + h * S_LEN + lane * 32;
    double run = 0.0;
#pragma unroll
    for (int e = 0; e < 32; ++e) { run += lsp[e]; cs0[e] = run; }
    double incl = run;
#pragma unroll
    for (int off = 1; off < 64; off <<= 1) {
      double nb = __shfl_up(incl, off);
      if (lane >= off) incl += nb;
    }
    double base = __shfl_up(incl, 1);
    if (lane == 0) base = 0.0;
#pragma unroll
    for (int e = 0; e < 32; ++e) cs0[e] += base;

    const float* igp = ig + h * S_LEN + lane * 32;
    double gv[32];
#pragma unroll
    for (int e = 0; e < 32; ++e) {
      gv[e] = (double)igp[e] - cs0[e];
      Lg[lane * 32 + e] = gv[e];
      Lcs[lane * 32 + e] = cs0[e];
    }
    double pm = -INFINITY;
#pragma unroll
    for (int e = 0; e < 32; ++e) { pm = fmax(pm, gv[e]); gv[e] = pm; }
    double inclm = pm;
#pragma unroll
    for (int off = 1; off < 64; off <<= 1) {
      double nb = __shfl_up(inclm, off);
      if (lane >= off) inclm = fmax(inclm, nb);
    }
    double basem = __shfl_up(inclm, 1);
    if (lane == 0) basem = -INFINITY;
#pragma unroll
    for (int e = 0; e < 32; ++e) LM[lane * 32 + e] = fmax(basem, gv[e]);
  }
  __syncthreads();

  const double L2E = 1.4426950408889634;
#pragma unroll
  for (int it = 0; it < 8; ++it) {
    int i = it * 256 + tid;
    int qgi = i >> 7;
    Mq[h * S_LEN + i] = (float)((LM[i] - LM[qgi * 128]) * L2E);
    rexpv[h * S_LEN + i] = __expf(-(float)(Lcs[i] + LM[i]));
  }
  for (int qg = 0; qg < 16; ++qg) {
    double base = LM[qg * 128];
    float* dst = gq + (size_t)(h * 16 + qg) * S_LEN;
#pragma unroll
    for (int it = 0; it < 8; ++it) {
      int j = it * 256 + tid;
      dst[j] = (float)((Lg[j] - base) * L2E);
    }
  }
}

// ---------- kernel 4: attention, 2-buf 48KB, 1 barrier/tile, balanced kv-splits ----------
__global__ __launch_bounds__(256, 2) void attn_kernel(
    const float* __restrict__ q,
    const __bf16* __restrict__ KfH, const __bf16* __restrict__ KfL,
    const __bf16* __restrict__ VT,
    const float* __restrict__ gq, const float* __restrict__ Mq,
    __bf16* __restrict__ part, float* __restrict__ bpart) {
  // decode: heavy-first (qg=15 first); block counts per qg = 8*ns(qg)
  int rem = blockIdx.x;
  int qg = 15, preLow = 0, ns = 1;
  for (int qq = 15; qq >= 0; --qq) {
    int n = ns_of(qq);
    if (rem < 8 * n) { qg = qq; ns = n; break; }
    rem -= 8 * n;
  }
  for (int qq = 0; qq < qg; ++qq) preLow += ns_of(qq);
  int h = rem & 7;                   // head -> XCD pinned
  int split = rem >> 3;
  int T = 4 * qg + 4;
  int kb_lo = (split * T) / ns;
  int kb_hi = ((split + 1) * T) / ns;
  int Tq = kb_hi - kb_lo;            // <= 10
  int tid = threadIdx.x, wave = tid >> 6, lane = tid & 63;
  int l31 = lane & 31, hi = lane >> 5;
  const float scale = 0.08838834764831845f;

  __shared__ char smem[49152];       // 2 bufs x [KH 8K | KL 8K | VT 8K]

  int qrow = qg * 128 + wave * 32 + l31;
  bf16x8 qfh[8], qfl[8];
  {
    const float* qp = q + (size_t)qrow * E_DIM + h * DHEAD + hi * 8;
#pragma unroll
    for (int kch = 0; kch < 8; ++kch) {
      float buf[8];
      *(float4*)&buf[0] = *(const float4*)(qp + kch * 16);
      *(float4*)&buf[4] = *(const float4*)(qp + kch * 16 + 4);
#pragma unroll
      for (int e = 0; e < 8; ++e) buf[e] *= scale;
      split8(buf, qfh[kch], qfl[kch]);
    }
  }
  float Mreg = Mq[h * S_LEN + qrow];
  const float* gqh = gq + (size_t)(h * 16 + qg) * S_LEN;

  f32x16 acc[4];
#pragma unroll
  for (int dt = 0; dt < 4; ++dt) acc[dt] = (f32x16)(0.f);
  float bacc = 0.f;

  size_t laneoff = (size_t)lane * 8;
  auto STAGE = [&](int kb, int buf) {
    size_t tb = (size_t)(h * 64 + kb) * 4096;
    char* lb = smem + buf * 24576;
#pragma unroll
    for (int i = 0; i < 6; ++i) {
      int c = wave * 6 + i;
      const __bf16* src;
      if (c < 8)       src = KfH + tb + (size_t)c * 512 + laneoff;
      else if (c < 16) src = KfL + tb + (size_t)(c - 8) * 512 + laneoff;
      else             src = VT  + tb + (size_t)(c - 16) * 512 + laneoff;
      __builtin_amdgcn_global_load_lds(
          (const __attribute__((address_space(1))) void*)src,
          (__attribute__((address_space(3))) void*)(lb + c * 1024), 16, 0, 0);
    }
  };

  if (Tq > 0) STAGE(kb_lo, 0);
  int cur = 0;
  for (int t = 0; t < Tq; ++t) {
    int kb = kb_lo + t;
    asm volatile("s_waitcnt vmcnt(0)" ::: "memory");
    __builtin_amdgcn_sched_barrier(0);
    asm volatile("s_barrier" ::: "memory");
    if (t + 1 < Tq) STAGE(kb + 1, cur ^ 1);   // flies during compute of tile t

    int qrelw = qg * 128 + wave * 32 - kb * 32;
    if (qrelw + 31 >= 0) {
      char* lb = smem + cur * 24576;
      int qrel = qrelw + l31;
      float4 g4[4];
#pragma unroll
      for (int c = 0; c < 4; ++c) g4[c] = *(const float4*)(gqh + kb * 32 + 8 * c + 4 * hi);
      // ---- S^T: 3 independent 8-MFMA chains (hh, lh, hl) ----
      f32x16 sA = (f32x16)(0.f), sB = (f32x16)(0.f), sC = (f32x16)(0.f);
      __builtin_amdgcn_s_setprio(1);
#pragma unroll
      for (int kch = 0; kch < 8; ++kch) {
        bf16x8 kh = *(const bf16x8*)(lb + kch * 1024 + lane * 16);
        bf16x8 kl = *(const bf16x8*)(lb + 8192 + kch * 1024 + lane * 16);
        sA = __builtin_amdgcn_mfma_f32_32x32x16_bf16(kh, qfh[kch], sA, 0, 0, 0);
        sB = __builtin_amdgcn_mfma_f32_32x32x16_bf16(kl, qfh[kch], sB, 0, 0, 0);
        sC = __builtin_amdgcn_mfma_f32_32x32x16_bf16(kh, qfl[kch], sC, 0, 0, 0);
      }
      __builtin_amdgcn_s_setprio(0);
      float p[16];
      float bp0 = 0.f, bp1 = 0.f, bp2 = 0.f, bp3 = 0.f;
      if (qrelw >= 31) {           // interior tile: no causal mask
#pragma unroll
        for (int rg = 0; rg < 16; ++rg) {
          float sv = sA[rg] + sB[rg] + sC[rg];
          p[rg] = sv * exp2f(((const float*)&g4[rg >> 2])[rg & 3] - Mreg);
          if ((rg & 3) == 0) bp0 += p[rg];
          else if ((rg & 3) == 1) bp1 += p[rg];
          else if ((rg & 3) == 2) bp2 += p[rg];
          else bp3 += p[rg];
        }
      } else {                     // diagonal tile
#pragma unroll
        for (int rg = 0; rg < 16; ++rg) {
          int J = (rg & 3) + 8 * (rg >> 2) + 4 * hi;
          float sv = sA[rg] + sB[rg] + sC[rg];
          float w = sv * exp2f(((const float*)&g4[rg >> 2])[rg & 3] - Mreg);
          p[rg] = (J <= qrel) ? w : 0.f;
          if ((rg & 3) == 0) bp0 += p[rg];
          else if ((rg & 3) == 1) bp1 += p[rg];
          else if ((rg & 3) == 2) bp2 += p[rg];
          else bp3 += p[rg];
        }
      }
      bacc += (bp0 + bp1) + (bp2 + bp3);
#pragma unroll
      for (int kch = 0; kch < 2; ++kch) {
        const float* pp = p + kch * 8;
        int a0 = cvtpk(pp[0], pp[1]);
        int a1 = cvtpk(pp[2], pp[3]);
        int a2 = cvtpk(pp[4], pp[5]);
        int a3 = cvtpk(pp[6], pp[7]);
        asm("v_permlane32_swap_b32 %0, %1" : "+v"(a0), "+v"(a2));
        asm("v_permlane32_swap_b32 %0, %1" : "+v"(a1), "+v"(a3));
        union { int w[4]; bf16x8 v; } pb;
        pb.w[0] = a0; pb.w[1] = a1; pb.w[2] = a2; pb.w[3] = a3;
        __builtin_amdgcn_s_setprio(1);
#pragma unroll
        for (int dt = 0; dt < 4; ++dt) {
          bf16x8 va = *(const bf16x8*)(lb + 16384 + (dt * 2 + kch) * 1024 + lane * 16);
          acc[dt] = __builtin_amdgcn_mfma_f32_32x32x16_bf16(va, pb.v, acc[dt], 0, 0, 0);
        }
        __builtin_amdgcn_s_setprio(0);
      }
    }
    cur ^= 1;    // next iter's top barrier is the sync point
  }

  // epilogue: b-combine; transpose O^T -> q-major via LDS; coalesced part writes
  {
    int x = __float_as_int(bacc), y = x;
    asm("v_permlane32_swap_b32 %0, %1" : "+v"(x), "+v"(y));
    float bfull = __int_as_float(x) + __int_as_float(y);
    int task = h * TASKS_PER_HEAD + preLow + split;
    if (lane < 32) bpart[task * 128 + wave * 32 + lane] = bfull;

    __syncthreads();                       // all waves done with K/V buffers
    char* Tls = smem + wave * 8704;        // 32 q x 272B
#pragma unroll
    for (int dt = 0; dt < 4; ++dt)
#pragma unroll
      for (int rgq = 0; rgq < 4; ++rgq) {
        bf16x4 pk;
        pk[0] = (__bf16)acc[dt][rgq * 4 + 0];
        pk[1] = (__bf16)acc[dt][rgq * 4 + 1];
        pk[2] = (__bf16)acc[dt][rgq * 4 + 2];
        pk[3] = (__bf16)acc[dt][rgq * 4 + 3];
        int d0 = dt * 32 + rgq * 8 + hi * 4;
        *(bf16x4*)(Tls + l31 * 272 + d0 * 2) = pk;
      }
    __syncthreads();
    __bf16* pp = part + (size_t)task * 16384;   // [128 q][128 d]
#pragma unroll
    for (int it = 0; it < 8; ++it) {
      int qr = it * 4 + (lane >> 4);
      int chunk = lane & 15;
      bf16x8 vrow = *(const bf16x8*)(Tls + qr * 272 + chunk * 16);
      *(bf16x8*)(pp + ((size_t)(wave * 32 + qr) * 128 + chunk * 8)) = vrow;
    }
  }
}

// ---------- kernel 5: fused combine + normalize + LayerNorm (variable ns) ----------
__global__ __launch_bounds__(256) void cln_kernel(
    const __bf16* __restrict__ part, const float* __restrict__ bpart,
    const float* __restrict__ rexpv, const float* __restrict__ lnw,
    float* __restrict__ out) {
  int b = blockIdx.x;            // 256 = qg*16 + slab
  int qg = b >> 4, slab = b & 15;
  int ns = ns_of(qg);
  int preLow = 0;
  for (int qq = 0; qq < qg; ++qq) preLow += ns_of(qq);
  int tid = threadIdx.x;
  int tokl = tid >> 5;
  int j = tid & 31;
  int qv = slab * 8 + tokl;
  int tok = qg * 128 + qv;
  int h = j >> 2;
  int d0 = (j & 3) * 32;
  int task0 = h * TASKS_PER_HEAD + preLow;

  float a[32];
#pragma unroll
  for (int i = 0; i < 32; ++i) a[i] = 0.f;
  float bb = 0.f;
  for (int s = 0; s < ns; ++s) {
    const __bf16* pp = part + (size_t)(task0 + s) * 16384 + qv * 128 + d0;
#pragma unroll
    for (int c = 0; c < 4; ++c) {
      bf16x8 xv = *(const bf16x8*)(pp + c * 8);
#pragma unroll
      for (int e = 0; e < 8; ++e) a[c * 8 + e] += (float)xv[e];
    }
    bb += bpart[(task0 + s) * 128 + qv];
  }
  float norm = fmaxf(fabsf(bb), rexpv[h * S_LEN + tok]) + MEPS;
  float inv = 1.f / norm;
  float sum = 0.f, sq = 0.f;
#pragma unroll
  for (int i = 0; i < 32; ++i) {
    a[i] *= inv;
    sum += a[i];
    sq += a[i] * a[i];
  }
#pragma unroll
  for (int off = 1; off < 32; off <<= 1) {
    sum += __shfl_xor(sum, off);
    sq  += __shfl_xor(sq, off);
  }
  float mu = sum * (1.f / E_DIM);
  float var = sq * (1.f / E_DIM) - mu * mu;
  float rstd = rsqrtf(var + LNEPS);
  float* dst = out + (size_t)tok * E_DIM + j * 32;
  const float* wsrc = lnw + j * 32;
#pragma unroll
  for (int c = 0; c < 8; ++c) {
    float4 w = *(const float4*)(wsrc + c * 4);
    float4 o;
    o.x = (a[c * 4 + 0] - mu) * rstd * w.x;
    o.y = (a[c * 4 + 1] - mu) * rstd * w.y;
    o.z = (a[c * 4 + 2] - mu) * rstd * w.z;
    o.w = (a[c * 4 + 3] - mu) * rstd * w.w;
    *(float4*)(dst + c * 4) = o;
  }
}

extern "C" void kernel_launch(void* const* d_in, const int* in_sizes, int n_in,
                              void* d_out, int out_size, void* d_ws, size_t ws_size,
                              hipStream_t stream) {
  const float* q   = (const float*)d_in[0];
  const float* k   = (const float*)d_in[1];
  const float* v   = (const float*)d_in[2];
  const float* igw = (const float*)d_in[3];
  const float* igb = (const float*)d_in[4];
  const float* fgw = (const float*)d_in[5];
  const float* fgb = (const float*)d_in[6];
  const float* lnw = (const float*)d_in[7];
  float* out = (float*)d_out;

  const size_t MB = 1024 * 1024;
  char* base = (char*)d_ws;
  float*  ig    = (float*)(base + 0);               // 64KB
  float*  rexpv = (float*)(base + 64 * 1024);       // 64KB
  float*  Mq    = (float*)(base + 128 * 1024);      // 64KB
  float*  bpart = (float*)(base + 192 * 1024);      // 488*128*4 = 250KB
  double* ls    = (double*)(base + 704 * 1024);     // 128KB
  __bf16* WfH   = (__bf16*)(base + 1088 * 1024);    // 96KB
  __bf16* WfL   = (__bf16*)(base + 1184 * 1024);    // 96KB
  float*  gq    = (float*)(base + 1536 * 1024);     // 1MB (ends 2.5MB)
  __bf16* KfH   = (__bf16*)(base + 3 * MB);         // 4MB
  __bf16* KfL   = (__bf16*)(base + 7 * MB);         // 4MB
  __bf16* VT    = (__bf16*)(base + 11 * MB);        // 4MB
  __bf16* part  = (__bf16*)(base + 15 * MB);        // 488 tasks x 32KB = 15.25MB
  float*  gpart = (float*)(base + 31 * MB);         // 1MB (footprint 32MB)

  int nblocks = 8 * TASKS_PER_HEAD;                 // 488

  convw_kernel<<<dim3(536), dim3(256), 0, stream>>>(k, v, igw, fgw, KfH, KfL, VT, WfH, WfL);
  gates_mfma_kernel<<<dim3(256), dim3(256), 0, stream>>>(q, k, v, WfH, WfL, gpart);
  combine_ls_kernel<<<dim3(128), dim3(256), 0, stream>>>(gpart, igb, fgb, ig, ls);
  scanreb_kernel<<<dim3(NHEAD), dim3(256), 0, stream>>>(ig, ls, gq, Mq, rexpv);
  attn_kernel<<<dim3(nblocks), dim3(256), 0, stream>>>(q, KfH, KfL, VT, gq, Mq, part, bpart);
  cln_kernel<<<dim3(256), dim3(256), 0, stream>>>(part, bpart, rexpv, lnw, out);
}

// Round 20
// 69.049 us; speedup vs baseline: 1.1532x; 1.0270x over previous
//
#include <hip/hip_runtime.h>
#include <hip/hip_bf16.h>
#include <math.h>

#define S_LEN 2048
#define E_DIM 1024
#define NHEAD 8
#define DHEAD 128
#define MEPS 1e-6f
#define LNEPS 1e-5f
#define TASKS_PER_HEAD 61   // sum over qg of ceil((4qg+4)/10)

typedef __bf16 bf16x8 __attribute__((ext_vector_type(8)));
typedef __bf16 bf16x4 __attribute__((ext_vector_type(4)));
typedef float f32x4 __attribute__((ext_vector_type(4)));
typedef float f32x16 __attribute__((ext_vector_type(16)));

__device__ __host__ inline int ns_of(int qg) { return (4 * qg + 13) / 10; }

__device__ inline void split8(const float* x, bf16x8& hi, bf16x8& lo) {
#pragma unroll
  for (int e = 0; e < 8; ++e) {
    float v = x[e];
    __bf16 h = (__bf16)v;
    hi[e] = h;
    lo[e] = (__bf16)(v - (float)h);
  }
}

__device__ inline int cvtpk(float a, float b) {
  int d;
  asm("v_cvt_pk_bf16_f32 %0, %1, %2" : "=v"(d) : "v"(a), "v"(b));
  return d;
}

// ---------- kernel A: fused prep = convert K/V (blocks 0..511) + gates GEMM (512..767) ----------
// gates branch loads W fragments straight from global (identical math to old wfrag+WfH/WfL path).
__global__ __launch_bounds__(256) void prep_kernel(
    const float* __restrict__ q, const float* __restrict__ k, const float* __restrict__ v,
    const float* __restrict__ igw, const float* __restrict__ fgw,
    __bf16* __restrict__ KfH, __bf16* __restrict__ KfL, __bf16* __restrict__ VT,
    float* __restrict__ gpart) {
  __shared__ float Sh[8448];   // union: convert 33.8KB (Kl+Vl) / gates 32KB (Xl)
  int t = threadIdx.x;

  if (blockIdx.x < 512) {
    // ---- convert K,V to 32x32-MFMA fragment layouts ----
    float (*Kl)[132] = (float(*)[132])Sh;
    float (*Vl)[132] = (float(*)[132])(Sh + 32 * 132);
    int h = blockIdx.x >> 6, kvt = blockIdx.x & 63;
    int kvbase = kvt * 32;
#pragma unroll
    for (int it = 0; it < 4; ++it) {
      int fid = it * 256 + t;
      int r = fid >> 5, c4 = (fid & 31) * 4;
      *(float4*)&Kl[r][c4] = *(const float4*)(k + (size_t)(kvbase + r) * E_DIM + h * DHEAD + c4);
      *(float4*)&Vl[r][c4] = *(const float4*)(v + (size_t)(kvbase + r) * E_DIM + h * DHEAD + c4);
    }
    __syncthreads();
    size_t tb = (size_t)(h * 64 + kvt) * 4096;
#pragma unroll
    for (int it = 0; it < 2; ++it) {
      int slot = it * 256 + t;
      int f = slot >> 6, l = slot & 63;
      int l31 = l & 31, hi = l >> 5;
      {
        float buf[8];
#pragma unroll
        for (int e = 0; e < 8; ++e) buf[e] = Kl[l31][f * 16 + hi * 8 + e];
        bf16x8 fh, fl; split8(buf, fh, fl);
        *(bf16x8*)(KfH + tb + (size_t)slot * 8) = fh;
        *(bf16x8*)(KfL + tb + (size_t)slot * 8) = fl;
      }
      {
        int dt = f >> 1, kch = f & 1;
        bf16x8 fh;
#pragma unroll
        for (int e = 0; e < 8; ++e) fh[e] = (__bf16)Vl[kch * 16 + hi * 8 + e][dt * 32 + l31];
        *(bf16x8*)(VT + tb + (size_t)slot * 8) = fh;
      }
    }
  } else {
    // ---- gates GEMM via split-bf16 MFMA, W loaded direct from global ----
    char* Xl = (char*)Sh;
    int bb = blockIdx.x - 512;
    int rb = bb >> 3;
    int ks = bb & 7;
    int r0 = rb * 64;
    int wave = t >> 6, lane = t & 63;
    int l15 = lane & 15, hi = lane >> 4;
    // lane's W row base: W[c=l15][ks*384 + hi*8 + ...]
    const float* wbase = (l15 < 8 ? igw + l15 * 3072 : fgw + (l15 - 8) * 3072) + ks * 384 + hi * 8;

    f32x4 cacc = (f32x4){0.f, 0.f, 0.f, 0.f};
    for (int ch = 0; ch < 3; ++ch) {
      int kb = ks * 384 + ch * 128;
      __syncthreads();
#pragma unroll
      for (int it = 0; it < 8; ++it) {
        int fid = it * 256 + t;
        int row = fid >> 5, c4 = (fid & 31) * 4;
        int kk = kb + c4;
        const float* src = (kk < 1024) ? (q + (size_t)(r0 + row) * 1024 + kk)
                         : (kk < 2048) ? (k + (size_t)(r0 + row) * 1024 + (kk - 1024))
                                       : (v + (size_t)(r0 + row) * 1024 + (kk - 2048));
        float4 xv = *(const float4*)src;
        *(float4*)(Xl + ((row * 512 + c4 * 4) ^ ((row & 7) << 4))) = xv;
      }
      __syncthreads();
#pragma unroll
      for (int kc = 0; kc < 4; ++kc) {
        int row = wave * 16 + l15;
        int base = row * 512 + (kc * 32 + hi * 8) * 4;
        int x = (row & 7) << 4;
        float buf[8];
        *(float4*)&buf[0] = *(const float4*)(Xl + (base ^ x));
        *(float4*)&buf[4] = *(const float4*)(Xl + ((base + 16) ^ x));
        bf16x8 ah, al; split8(buf, ah, al);
        float wb[8];
        const float* wr = wbase + (ch * 4 + kc) * 32;
        *(float4*)&wb[0] = *(const float4*)wr;
        *(float4*)&wb[4] = *(const float4*)(wr + 4);
        bf16x8 bh, bl; split8(wb, bh, bl);
        cacc = __builtin_amdgcn_mfma_f32_16x16x32_bf16(ah, bh, cacc, 0, 0, 0);
        cacc = __builtin_amdgcn_mfma_f32_16x16x32_bf16(ah, bl, cacc, 0, 0, 0);
        cacc = __builtin_amdgcn_mfma_f32_16x16x32_bf16(al, bh, cacc, 0, 0, 0);
      }
    }
#pragma unroll
    for (int rg = 0; rg < 4; ++rg) {
      int r = r0 + wave * 16 + hi * 4 + rg;
      gpart[((size_t)ks * S_LEN + r) * 16 + l15] = cacc[rg];
    }
  }
}

// ---------- kernel 1b: sum K-split partials + bias; ig f32, fg -> f64 logsig ----------
__global__ __launch_bounds__(256) void combine_ls_kernel(
    const float* __restrict__ gpart, const float* __restrict__ igb,
    const float* __restrict__ fgb, float* __restrict__ ig, double* __restrict__ ls) {
  int t = blockIdx.x * 256 + threadIdx.x;
  int r = t >> 4, c = t & 15;
  float s = 0.f;
#pragma unroll
  for (int ks = 0; ks < 8; ++ks) s += gpart[((size_t)ks * S_LEN + r) * 16 + c];
  if (c < 8) {
    ig[c * S_LEN + r] = s + igb[c];
  } else {
    double x = (double)(s + fgb[c - 8]);
    ls[(c - 8) * S_LEN + r] = fmin(x, 0.0) - log1p(exp(-fabs(x)));
  }
}

// ---------- kernel 2: fused per-head f64 scan + rebase (1 block/head, 256 thr) ----------
__global__ __launch_bounds__(256) void scanreb_kernel(
    const float* __restrict__ ig, const double* __restrict__ ls,
    float* __restrict__ gq, float* __restrict__ Mq, float* __restrict__ rexpv) {
  int h = blockIdx.x;
  int tid = threadIdx.x;
  __shared__ double Lg[2048];
  __shared__ double Lcs[2048];
  __shared__ double LM[2048];

  if (tid < 64) {
    int lane = tid;
    double cs0[32];
    const double* lsp = ls + h * S_LEN + lane * 32;
    double run = 0.0;
#pragma unroll
    for (int e = 0; e < 32; ++e) { run += lsp[e]; cs0[e] = run; }
    double incl = run;
#pragma unroll
    for (int off = 1; off < 64; off <<= 1) {
      double nb = __shfl_up(incl, off);
      if (lane >= off) incl += nb;
    }
    double base = __shfl_up(incl, 1);
    if (lane == 0) base = 0.0;
#pragma unroll
    for (int e = 0; e < 32; ++e) cs0[e] += base;

    const float* igp = ig + h * S_LEN + lane * 32;
    double gv[32];
#pragma unroll
    for (int e = 0; e < 32; ++e) {
      gv[e] = (double)igp[e] - cs0[e];
      Lg[lane * 32 + e] = gv[e];
      Lcs[lane * 32 + e] = cs0[e];
    }
    double pm = -INFINITY;
#pragma unroll
    for (int e = 0; e < 32; ++e) { pm = fmax(pm, gv[e]); gv[e] = pm; }
    double inclm = pm;
#pragma unroll
    for (int off = 1; off < 64; off <<= 1) {
      double nb = __shfl_up(inclm, off);
      if (lane >= off) inclm = fmax(inclm, nb);
    }
    double basem = __shfl_up(inclm, 1);
    if (lane == 0) basem = -INFINITY;
#pragma unroll
    for (int e = 0; e < 32; ++e) LM[lane * 32 + e] = fmax(basem, gv[e]);
  }
  __syncthreads();

  const double L2E = 1.4426950408889634;
#pragma unroll
  for (int it = 0; it < 8; ++it) {
    int i = it * 256 + tid;
    int qgi = i >> 7;
    Mq[h * S_LEN + i] = (float)((LM[i] - LM[qgi * 128]) * L2E);
    rexpv[h * S_LEN + i] = __expf(-(float)(Lcs[i] + LM[i]));
  }
  for (int qg = 0; qg < 16; ++qg) {
    double base = LM[qg * 128];
    float* dst = gq + (size_t)(h * 16 + qg) * S_LEN;
#pragma unroll
    for (int it = 0; it < 8; ++it) {
      int j = it * 256 + tid;
      dst[j] = (float)((Lg[j] - base) * L2E);
    }
  }
}

// ---------- kernel 4: attention, 2-buf 48KB, 1 barrier/tile, balanced kv-splits ----------
__global__ __launch_bounds__(256, 2) void attn_kernel(
    const float* __restrict__ q,
    const __bf16* __restrict__ KfH, const __bf16* __restrict__ KfL,
    const __bf16* __restrict__ VT,
    const float* __restrict__ gq, const float* __restrict__ Mq,
    __bf16* __restrict__ part, float* __restrict__ bpart) {
  int rem = blockIdx.x;
  int qg = 15, preLow = 0, ns = 1;
  for (int qq = 15; qq >= 0; --qq) {
    int n = ns_of(qq);
    if (rem < 8 * n) { qg = qq; ns = n; break; }
    rem -= 8 * n;
  }
  for (int qq = 0; qq < qg; ++qq) preLow += ns_of(qq);
  int h = rem & 7;
  int split = rem >> 3;
  int T = 4 * qg + 4;
  int kb_lo = (split * T) / ns;
  int kb_hi = ((split + 1) * T) / ns;
  int Tq = kb_hi - kb_lo;            // <= 10
  int tid = threadIdx.x, wave = tid >> 6, lane = tid & 63;
  int l31 = lane & 31, hi = lane >> 5;
  const float scale = 0.08838834764831845f;

  __shared__ char smem[49152];       // 2 bufs x [KH 8K | KL 8K | VT 8K]

  int qrow = qg * 128 + wave * 32 + l31;
  bf16x8 qfh[8], qfl[8];
  {
    const float* qp = q + (size_t)qrow * E_DIM + h * DHEAD + hi * 8;
#pragma unroll
    for (int kch = 0; kch < 8; ++kch) {
      float buf[8];
      *(float4*)&buf[0] = *(const float4*)(qp + kch * 16);
      *(float4*)&buf[4] = *(const float4*)(qp + kch * 16 + 4);
#pragma unroll
      for (int e = 0; e < 8; ++e) buf[e] *= scale;
      split8(buf, qfh[kch], qfl[kch]);
    }
  }
  float Mreg = Mq[h * S_LEN + qrow];
  const float* gqh = gq + (size_t)(h * 16 + qg) * S_LEN;

  f32x16 acc[4];
#pragma unroll
  for (int dt = 0; dt < 4; ++dt) acc[dt] = (f32x16)(0.f);
  float bacc = 0.f;

  size_t laneoff = (size_t)lane * 8;
  auto STAGE = [&](int kb, int buf) {
    size_t tb = (size_t)(h * 64 + kb) * 4096;
    char* lb = smem + buf * 24576;
#pragma unroll
    for (int i = 0; i < 6; ++i) {
      int c = wave * 6 + i;
      const __bf16* src;
      if (c < 8)       src = KfH + tb + (size_t)c * 512 + laneoff;
      else if (c < 16) src = KfL + tb + (size_t)(c - 8) * 512 + laneoff;
      else             src = VT  + tb + (size_t)(c - 16) * 512 + laneoff;
      __builtin_amdgcn_global_load_lds(
          (const __attribute__((address_space(1))) void*)src,
          (__attribute__((address_space(3))) void*)(lb + c * 1024), 16, 0, 0);
    }
  };

  if (Tq > 0) STAGE(kb_lo, 0);
  int cur = 0;
  for (int t = 0; t < Tq; ++t) {
    int kb = kb_lo + t;
    asm volatile("s_waitcnt vmcnt(0)" ::: "memory");
    __builtin_amdgcn_sched_barrier(0);
    asm volatile("s_barrier" ::: "memory");
    if (t + 1 < Tq) STAGE(kb + 1, cur ^ 1);

    int qrelw = qg * 128 + wave * 32 - kb * 32;
    if (qrelw + 31 >= 0) {
      char* lb = smem + cur * 24576;
      int qrel = qrelw + l31;
      float4 g4[4];
#pragma unroll
      for (int c = 0; c < 4; ++c) g4[c] = *(const float4*)(gqh + kb * 32 + 8 * c + 4 * hi);
      f32x16 sA = (f32x16)(0.f), sB = (f32x16)(0.f), sC = (f32x16)(0.f);
      __builtin_amdgcn_s_setprio(1);
#pragma unroll
      for (int kch = 0; kch < 8; ++kch) {
        bf16x8 kh = *(const bf16x8*)(lb + kch * 1024 + lane * 16);
        bf16x8 kl = *(const bf16x8*)(lb + 8192 + kch * 1024 + lane * 16);
        sA = __builtin_amdgcn_mfma_f32_32x32x16_bf16(kh, qfh[kch], sA, 0, 0, 0);
        sB = __builtin_amdgcn_mfma_f32_32x32x16_bf16(kl, qfh[kch], sB, 0, 0, 0);
        sC = __builtin_amdgcn_mfma_f32_32x32x16_bf16(kh, qfl[kch], sC, 0, 0, 0);
      }
      __builtin_amdgcn_s_setprio(0);
      float p[16];
      float bp0 = 0.f, bp1 = 0.f, bp2 = 0.f, bp3 = 0.f;
      if (qrelw >= 31) {
#pragma unroll
        for (int rg = 0; rg < 16; ++rg) {
          float sv = sA[rg] + sB[rg] + sC[rg];
          p[rg] = sv * exp2f(((const float*)&g4[rg >> 2])[rg & 3] - Mreg);
          if ((rg & 3) == 0) bp0 += p[rg];
          else if ((rg & 3) == 1) bp1 += p[rg];
          else if ((rg & 3) == 2) bp2 += p[rg];
          else bp3 += p[rg];
        }
      } else {
#pragma unroll
        for (int rg = 0; rg < 16; ++rg) {
          int J = (rg & 3) + 8 * (rg >> 2) + 4 * hi;
          float sv = sA[rg] + sB[rg] + sC[rg];
          float w = sv * exp2f(((const float*)&g4[rg >> 2])[rg & 3] - Mreg);
          p[rg] = (J <= qrel) ? w : 0.f;
          if ((rg & 3) == 0) bp0 += p[rg];
          else if ((rg & 3) == 1) bp1 += p[rg];
          else if ((rg & 3) == 2) bp2 += p[rg];
          else bp3 += p[rg];
        }
      }
      bacc += (bp0 + bp1) + (bp2 + bp3);
#pragma unroll
      for (int kch = 0; kch < 2; ++kch) {
        const float* pp = p + kch * 8;
        int a0 = cvtpk(pp[0], pp[1]);
        int a1 = cvtpk(pp[2], pp[3]);
        int a2 = cvtpk(pp[4], pp[5]);
        int a3 = cvtpk(pp[6], pp[7]);
        asm("v_permlane32_swap_b32 %0, %1" : "+v"(a0), "+v"(a2));
        asm("v_permlane32_swap_b32 %0, %1" : "+v"(a1), "+v"(a3));
        union { int w[4]; bf16x8 v; } pb;
        pb.w[0] = a0; pb.w[1] = a1; pb.w[2] = a2; pb.w[3] = a3;
        __builtin_amdgcn_s_setprio(1);
#pragma unroll
        for (int dt = 0; dt < 4; ++dt) {
          bf16x8 va = *(const bf16x8*)(lb + 16384 + (dt * 2 + kch) * 1024 + lane * 16);
          acc[dt] = __builtin_amdgcn_mfma_f32_32x32x16_bf16(va, pb.v, acc[dt], 0, 0, 0);
        }
        __builtin_amdgcn_s_setprio(0);
      }
    }
    cur ^= 1;
  }

  // epilogue
  {
    int x = __float_as_int(bacc), y = x;
    asm("v_permlane32_swap_b32 %0, %1" : "+v"(x), "+v"(y));
    float bfull = __int_as_float(x) + __int_as_float(y);
    int task = h * TASKS_PER_HEAD + preLow + split;
    if (lane < 32) bpart[task * 128 + wave * 32 + lane] = bfull;

    __syncthreads();
    char* Tls = smem + wave * 8704;
#pragma unroll
    for (int dt = 0; dt < 4; ++dt)
#pragma unroll
      for (int rgq = 0; rgq < 4; ++rgq) {
        bf16x4 pk;
        pk[0] = (__bf16)acc[dt][rgq * 4 + 0];
        pk[1] = (__bf16)acc[dt][rgq * 4 + 1];
        pk[2] = (__bf16)acc[dt][rgq * 4 + 2];
        pk[3] = (__bf16)acc[dt][rgq * 4 + 3];
        int d0 = dt * 32 + rgq * 8 + hi * 4;
        *(bf16x4*)(Tls + l31 * 272 + d0 * 2) = pk;
      }
    __syncthreads();
    __bf16* pp = part + (size_t)task * 16384;
#pragma unroll
    for (int it = 0; it < 8; ++it) {
      int qr = it * 4 + (lane >> 4);
      int chunk = lane & 15;
      bf16x8 vrow = *(const bf16x8*)(Tls + qr * 272 + chunk * 16);
      *(bf16x8*)(pp + ((size_t)(wave * 32 + qr) * 128 + chunk * 8)) = vrow;
    }
  }
}

// ---------- kernel 5: fused combine + normalize + LayerNorm (variable ns) ----------
__global__ __launch_bounds__(256) void cln_kernel(
    const __bf16* __restrict__ part, const float* __restrict__ bpart,
    const float* __restrict__ rexpv, const float* __restrict__ lnw,
    float* __restrict__ out) {
  int b = blockIdx.x;
  int qg = b >> 4, slab = b & 15;
  int ns = ns_of(qg);
  int preLow = 0;
  for (int qq = 0; qq < qg; ++qq) preLow += ns_of(qq);
  int tid = threadIdx.x;
  int tokl = tid >> 5;
  int j = tid & 31;
  int qv = slab * 8 + tokl;
  int tok = qg * 128 + qv;
  int h = j >> 2;
  int d0 = (j & 3) * 32;
  int task0 = h * TASKS_PER_HEAD + preLow;

  float a[32];
#pragma unroll
  for (int i = 0; i < 32; ++i) a[i] = 0.f;
  float bb = 0.f;
  for (int s = 0; s < ns; ++s) {
    const __bf16* pp = part + (size_t)(task0 + s) * 16384 + qv * 128 + d0;
#pragma unroll
    for (int c = 0; c < 4; ++c) {
      bf16x8 xv = *(const bf16x8*)(pp + c * 8);
#pragma unroll
      for (int e = 0; e < 8; ++e) a[c * 8 + e] += (float)xv[e];
    }
    bb += bpart[(task0 + s) * 128 + qv];
  }
  float norm = fmaxf(fabsf(bb), rexpv[h * S_LEN + tok]) + MEPS;
  float inv = 1.f / norm;
  float sum = 0.f, sq = 0.f;
#pragma unroll
  for (int i = 0; i < 32; ++i) {
    a[i] *= inv;
    sum += a[i];
    sq += a[i] * a[i];
  }
#pragma unroll
  for (int off = 1; off < 32; off <<= 1) {
    sum += __shfl_xor(sum, off);
    sq  += __shfl_xor(sq, off);
  }
  float mu = sum * (1.f / E_DIM);
  float var = sq * (1.f / E_DIM) - mu * mu;
  float rstd = rsqrtf(var + LNEPS);
  float* dst = out + (size_t)tok * E_DIM + j * 32;
  const float* wsrc = lnw + j * 32;
#pragma unroll
  for (int c = 0; c < 8; ++c) {
    float4 w = *(const float4*)(wsrc + c * 4);
    float4 o;
    o.x = (a[c * 4 + 0] - mu) * rstd * w.x;
    o.y = (a[c * 4 + 1] - mu) * rstd * w.y;
    o.z = (a[c * 4 + 2] - mu) * rstd * w.z;
    o.w = (a[c * 4 + 3] - mu) * rstd * w.w;
    *(float4*)(dst + c * 4) = o;
  }
}

extern "C" void kernel_launch(void* const* d_in, const int* in_sizes, int n_in,
                              void* d_out, int out_size, void* d_ws, size_t ws_size,
                              hipStream_t stream) {
  const float* q   = (const float*)d_in[0];
  const float* k   = (const float*)d_in[1];
  const float* v   = (const float*)d_in[2];
  const float* igw = (const float*)d_in[3];
  const float* igb = (const float*)d_in[4];
  const float* fgw = (const float*)d_in[5];
  const float* fgb = (const float*)d_in[6];
  const float* lnw = (const float*)d_in[7];
  float* out = (float*)d_out;

  const size_t MB = 1024 * 1024;
  char* base = (char*)d_ws;
  float*  ig    = (float*)(base + 0);               // 64KB
  float*  rexpv = (float*)(base + 64 * 1024);       // 64KB
  float*  Mq    = (float*)(base + 128 * 1024);      // 64KB
  float*  bpart = (float*)(base + 192 * 1024);      // 250KB
  double* ls    = (double*)(base + 704 * 1024);     // 128KB
  float*  gq    = (float*)(base + 1536 * 1024);     // 1MB (ends 2.5MB)
  __bf16* KfH   = (__bf16*)(base + 3 * MB);         // 4MB
  __bf16* KfL   = (__bf16*)(base + 7 * MB);         // 4MB
  __bf16* VT    = (__bf16*)(base + 11 * MB);        // 4MB
  __bf16* part  = (__bf16*)(base + 15 * MB);        // 15.25MB
  float*  gpart = (float*)(base + 31 * MB);         // 1MB (footprint 32MB)

  int nblocks = 8 * TASKS_PER_HEAD;                 // 488

  prep_kernel<<<dim3(768), dim3(256), 0, stream>>>(q, k, v, igw, fgw, KfH, KfL, VT, gpart);
  combine_ls_kernel<<<dim3(128), dim3(256), 0, stream>>>(gpart, igb, fgb, ig, ls);
  scanreb_kernel<<<dim3(NHEAD), dim3(256), 0, stream>>>(ig, ls, gq, Mq, rexpv);
  attn_kernel<<<dim3(nblocks), dim3(256), 0, stream>>>(q, KfH, KfL, VT, gq, Mq, part, bpart);
  cln_kernel<<<dim3(256), dim3(256), 0, stream>>>(part, bpart, rexpv, lnw, out);
}